// Round 2
// baseline (380.778 us; speedup 1.0000x reference)
//
#include <hip/hip_runtime.h>

#define HP   768      // padded H (=W)
#define NV   385      // HP/2 + 1
#define HIN  512
#define WIN  512
#define K    8        // truncation radius of spatial inverse kernel
#define A    17       // 2K+1
#define PADO 136      // PAD + K = 128 + 8
#define TW   64       // output tile width
#define TH   64       // output tile height (2 rows per thread)
#define LH   80       // TH + 2K
#define LWL  80       // TW + 2K (logical tile width)
#define LWS  84       // padded LDS row stride (20*ty mod 32 spreads banks)
#define HROWS 40      // rows per parity half-tile
#define HSIZE (HROWS * LWS)   // 3360 floats per half-tile

#define OB   120      // active-region origin: nonzero out rows/cols = [120, 648)
#define OE   648      // active-region end (exclusive)
#define NT9  9        // 9x9 tiles cover [120, 696) >= [120, 648)
#define ACT0_Q 30     // 120/4  (float4 index of active col start)
#define ACT1_Q 174    // 696/4  (float4 index of active col end)

#define TWO_PI_OVER_HP 0.008181230868723419f  // 2*pi/768

typedef float f4v __attribute__((ext_vector_type(4)));

__device__ inline float2 cmul(float2 a, float2 b) {
    return make_float2(a.x*b.x - a.y*b.y, a.x*b.y + a.y*b.x);
}

// F(u,v) = sum_{i<3,j<3} w[i,j] * exp(-2*pi*i*(u*i + v*j)/768), via LDS table
__device__ inline float2 evalF_t(int u, int v, const float* w9,
                                 const float2* __restrict__ tbl) {
    float fr = 0.f, fi = 0.f;
#pragma unroll
    for (int i = 0; i < 3; ++i) {
#pragma unroll
        for (int j = 0; j < 3; ++j) {
            int idx = u * i + v * j;          // <= 2302
            if (idx >= 2 * HP) idx -= 2 * HP;
            if (idx >= HP)     idx -= HP;
            float2 e = tbl[idx];
            float wv = w9[i * 3 + j];
            fr += wv * e.x;
            fi -= wv * e.y;
        }
    }
    return make_float2(fr, fi);
}

// One block per rfft column v. Builds gmf[.,v] in LDS, then
// P[a,v] = sum_u gmf[u,v] * exp(+2*pi*i*u*(a-K)/768)  for all 17 taps,
// parallelized 16 threads per tap.
__global__ __launch_bounds__(320) void filt_P_kernel(
        const float* __restrict__ w, float2* __restrict__ P) {
    __shared__ float2 tbl[HP];
    __shared__ float2 lg[HP];
    __shared__ float2 red[20][16];
    int v = blockIdx.x;
    int tid = threadIdx.x;

    float w9[9];
#pragma unroll
    for (int i = 0; i < 9; ++i) w9[i] = w[i];

    for (int m = tid; m < HP; m += 320) {
        float s, c;
        sincosf((float)m * TWO_PI_OVER_HP, &s, &c);
        tbl[m] = make_float2(c, s);
    }
    __syncthreads();

    int sv = (v == 0) ? 0 : (NV - v);   // reference's reverse+roll index
    for (int u = tid; u < HP; u += 320) {
        int su = (HP - u) % HP;
        float2 F1 = evalF_t(u,  v,  w9, tbl);
        float2 F2 = evalF_t(su, v,  w9, tbl);
        float2 F3 = evalF_t(u,  sv, w9, tbl);
        float2 F4 = evalF_t(su, sv, w9, tbl);
        float2 pr = cmul(cmul(F1, F2), cmul(F3, F4));
        float d = pr.x * pr.x + pr.y * pr.y;
        lg[u] = make_float2(pr.x / d, -pr.y / d);   // 1/prod
    }
    __syncthreads();

    int a   = tid >> 4;   // 0..19 (taps 0..16 valid)
    int sub = tid & 15;
    if (a < A) {
        int ap  = a - K;
        int apu = (ap < 0) ? ap + HP : ap;
        float Pr = 0.f, Pi = 0.f;
        for (int u = sub; u < HP; u += 16) {
            int idx = (u * apu) % HP;
            float2 e = tbl[idx];
            float2 g = lg[u];
            Pr += g.x * e.x - g.y * e.y;
            Pi += g.x * e.y + g.y * e.x;
        }
        red[a][sub] = make_float2(Pr, Pi);
    }
    __syncthreads();
    if (tid < A) {
        float Pr = 0.f, Pi = 0.f;
#pragma unroll
        for (int s2 = 0; s2 < 16; ++s2) { Pr += red[tid][s2].x; Pi += red[tid][s2].y; }
        P[tid * NV + v] = make_float2(Pr, Pi);
    }
}

// g[a,b] = (1/768^2) * sum_v w_v * Re(P[a,v] * exp(+2*pi*i*v*(b-K)/768))
// Stored FLIPPED: gkf[(16-a)*17 + (16-b)] = g[a,b], so deconv reads ascending.
__global__ __launch_bounds__(256) void filt_gk_kernel(
        const float2* __restrict__ P, float* __restrict__ gkf) {
    __shared__ float2 tbl[HP];
    int tid = threadIdx.x;
    int id = blockIdx.x * 256 + tid;
    for (int m = tid; m < HP; m += 256) {
        float s, c;
        sincosf((float)m * TWO_PI_OVER_HP, &s, &c);
        tbl[m] = make_float2(c, s);
    }
    __syncthreads();
    if (id >= A * A) return;
    int ai = id / A;
    int bi = id - ai * A;
    int bp = bi - K;
    int bpu = (bp < 0) ? bp + HP : bp;
    float sum = 0.f;
    int idx = 0;
    for (int vv = 0; vv < NV; ++vv) {
        float wv = (vv == 0 || vv == NV - 1) ? 1.f : 2.f;
        float2 e = tbl[idx];
        float2 p = P[ai * NV + vv];
        sum += wv * (p.x * e.x - p.y * e.y);
        idx += bpu;
        if (idx >= HP) idx -= HP;
    }
    gkf[(2 * K - ai) * A + (2 * K - bi)] = sum * (1.f / ((float)HP * (float)HP));
}

// Zero everything outside the deconv-covered square [OB, OB+9*64) x [OB, OB+9*64).
// One wave per output row; nontemporal float4 stores (write-once data).
__global__ __launch_bounds__(256) void zero_border_kernel(float* __restrict__ out) {
    int gid  = blockIdx.x;            // 64 imgs * 192 row-groups
    int img  = gid / 192;
    int rg   = gid - img * 192;
    int lane = threadIdx.x & 63;
    int w    = threadIdx.x >> 6;      // wave 0..3 -> one row each
    int row  = rg * 4 + w;
    f4v* base = (f4v*)(out + ((size_t)img * HP + row) * HP);
    f4v z = {0.f, 0.f, 0.f, 0.f};
    if (row >= OB && row < OB + NT9 * TH) {
        // side strips: cols [0,120) and [696,768)
        if (lane < ACT0_Q)
            __builtin_nontemporal_store(z, base + lane);
        else if (lane < ACT0_Q + (192 - ACT1_Q))
            __builtin_nontemporal_store(z, base + ACT1_Q + (lane - ACT0_Q));
    } else {
        // full row: 192 float4 = 64 lanes x 3
        __builtin_nontemporal_store(z, base + lane);
        __builtin_nontemporal_store(z, base + lane + 64);
        __builtin_nontemporal_store(z, base + lane + 128);
    }
}

// Direct 17x17 convolution of zero-padded x into the 768x768 output grid,
// tiled over the 9x9 active region only (origin OB=120).
// Block (8,32); tile 64x64 outputs; thread computes 8 cols x 2 adjacent rows
// with a rolling register row-buffer (1 new LDS row per tap).
__global__ __launch_bounds__(256, 4) void deconv_kernel(
        const float* __restrict__ x, const float* __restrict__ gkf,
        float* __restrict__ out) {
    // parity-split tile: even tile-rows in [0], odd in [1] (bank spread)
    __shared__ __align__(16) float tile[2 * HSIZE];   // 26880 B

    const int tx = threadIdx.x;   // 0..7
    const int ty = threadIdx.y;   // 0..31
    const int tid = ty * 8 + tx;
    const int bx = blockIdx.x, by = blockIdx.y, bz = blockIdx.z;

    const int ix0 = bx * TW + (OB - PADO);   // = 64*bx - 16  (% 4 == 0)
    const int iy0 = by * TH + (OB - PADO);
    const int oy0 = OB + by * TH + ty * 2;
    const int ox0 = OB + bx * TW + tx * 8;
    float* orow0 = out + ((size_t)bz * HP + oy0) * HP + ox0;
    float* orow1 = orow0 + HP;

    // stage input tile (float4-granular; ix0 % 4 == 0 so no partial float4)
    const float* xb = x + (size_t)bz * (HIN * WIN);
    for (int l = tid; l < LH * (LWL / 4); l += 256) {   // 80*20 = 1600
        int r = l / 20, c4 = l - r * 20;
        int gy = iy0 + r;
        int gx = ix0 + c4 * 4;
        float4 val = make_float4(0.f, 0.f, 0.f, 0.f);
        if ((unsigned)gy < (unsigned)HIN && (unsigned)gx < (unsigned)WIN)
            val = *(const float4*)&xb[gy * WIN + gx];
        *(float4*)&tile[(r & 1) * HSIZE + (r >> 1) * LWS + c4 * 4] = val;
    }
    __syncthreads();

    // Wave-uniform early-out: output rows >= OE are provably zero (input
    // support ends at padded row 640; taps reach at most +8 => out < 648).
    // ty >= 8 in by==8 tiles -> waves 1..3 retire after staging (saves the
    // full 4624-FMA loop for 48 of 64 rows in the last tile row).
    if (oy0 >= OE) {
        f4v z = {0.f, 0.f, 0.f, 0.f};
        __builtin_nontemporal_store(z, (f4v*)orow0);
        __builtin_nontemporal_store(z, (f4v*)orow0 + 1);
        __builtin_nontemporal_store(z, (f4v*)orow1);
        __builtin_nontemporal_store(z, (f4v*)orow1 + 1);
        return;
    }

    const float* tE = tile;           // tile rows 0,2,4,...
    const float* tO = tile + HSIZE;   // tile rows 1,3,5,...

    float accA[8], accB[8];
#pragma unroll
    for (int c = 0; c < 8; ++c) { accA[c] = 0.f; accB[c] = 0.f; }
    float rbA[24], rbB[24];

    auto loadRow = [&](float* rb, const float* tb, int rowp) {
        const float* p = tb + rowp * LWS + tx * 8;
#pragma unroll
        for (int q = 0; q < 6; ++q)
            *(float4*)&rb[q * 4] = *(const float4*)&p[q * 4];
    };
    // gp is wave-uniform -> scalar loads; v_fmac with SGPR src0.
    // One row, one accumulator: lets the scheduler issue the full 136-FMA
    // block on the resident row before any FMA that waits on in-flight LDS.
    auto fmaRow = [&](const float* gp, const float* r, float* acc) {
#pragma unroll
        for (int bb = 0; bb < A; ++bb) {
            float g = gp[bb];
#pragma unroll
            for (int c = 0; c < 8; ++c)
                acc[c] += g * r[bb + c];
        }
    };

    loadRow(rbA, tE, ty);                      // input tile-row 2ty
#pragma unroll 1
    for (int aa = 0; aa < 16; aa += 2) {
        int h = aa >> 1;
        loadRow(rbB, tO, ty + h);              // row 2ty+aa+1 (in flight)
        fmaRow(gkf + aa * A, rbA, accA);       // tap aa -> out row0 (resident)
        fmaRow(gkf + aa * A, rbB, accB);       // tap aa -> out row1 (waits)
        loadRow(rbA, tE, ty + h + 1);          // row 2ty+aa+2 (in flight)
        fmaRow(gkf + (aa + 1) * A, rbB, accA); // tap aa+1 -> out row0 (resident)
        fmaRow(gkf + (aa + 1) * A, rbA, accB); // tap aa+1 -> out row1 (waits)
    }
    loadRow(rbB, tO, ty + 8);                  // row 2ty+17
    fmaRow(gkf + 16 * A, rbA, accA);           // tap 16
    fmaRow(gkf + 16 * A, rbB, accB);

    f4v vA0 = {accA[0], accA[1], accA[2], accA[3]};
    f4v vA1 = {accA[4], accA[5], accA[6], accA[7]};
    f4v vB0 = {accB[0], accB[1], accB[2], accB[3]};
    f4v vB1 = {accB[4], accB[5], accB[6], accB[7]};
    __builtin_nontemporal_store(vA0, (f4v*)orow0);
    __builtin_nontemporal_store(vA1, (f4v*)orow0 + 1);
    __builtin_nontemporal_store(vB0, (f4v*)orow1);
    __builtin_nontemporal_store(vB1, (f4v*)orow1 + 1);
}

extern "C" void kernel_launch(void* const* d_in, const int* in_sizes, int n_in,
                              void* d_out, int out_size, void* d_ws, size_t ws_size,
                              hipStream_t stream) {
    const float* x = (const float*)d_in[0];   // (64, 512, 512) fp32
    const float* w = (const float*)d_in[1];   // (3, 3) fp32
    float* out = (float*)d_out;               // (64, 768, 768) fp32

    // workspace layout (floats): P = A*NV float2, then gkf = A*A floats
    float2* P   = (float2*)d_ws;
    float*  gkf = (float*)d_ws + (size_t)A * NV * 2;

    filt_P_kernel<<<dim3(NV), dim3(320), 0, stream>>>(w, P);
    filt_gk_kernel<<<dim3(2), dim3(256), 0, stream>>>(P, gkf);
    zero_border_kernel<<<dim3(64 * 192), dim3(256), 0, stream>>>(out);
    deconv_kernel<<<dim3(NT9, NT9, 64), dim3(8, 32), 0, stream>>>(x, gkf, out);
}

// Round 4
// 317.257 us; speedup vs baseline: 1.2002x; 1.2002x over previous
//
#include <hip/hip_runtime.h>

#define HP   768      // padded H (=W)
#define NV   385      // HP/2 + 1
#define HIN  512
#define WIN  512
#define K    8        // truncation radius of spatial inverse kernel
#define A    17       // 2K+1
#define PADO 136      // PAD + K = 128 + 8
#define TW   64       // output tile width
#define TH   64       // output tile height (2 rows per thread)
#define LH   80       // TH + 2K
#define LWL  80       // TW + 2K (logical tile width)
#define LWS  84       // padded LDS row stride (20*ty mod 32 spreads banks)
#define HROWS 40      // rows per parity half-tile
#define HSIZE (HROWS * LWS)   // 3360 floats per half-tile

#define OB   120      // active-region origin: nonzero out rows/cols = [120, 648)
#define OE   648      // active-region end (exclusive)
#define NT9  9        // 9x9 tiles cover [120, 696) >= [120, 648)
#define ACT0_Q 30     // 120/4  (float4 index of active col start)
#define ACT1_Q 174    // 696/4  (float4 index of active col end)

#define TWO_PI_OVER_HP 0.008181230868723419f  // 2*pi/768

typedef float f4v __attribute__((ext_vector_type(4)));

__device__ inline float2 cmul(float2 a, float2 b) {
    return make_float2(a.x*b.x - a.y*b.y, a.x*b.y + a.y*b.x);
}

// F(u,v) = sum_{i<3,j<3} w[i,j] * exp(-2*pi*i*(u*i + v*j)/768), via LDS table
__device__ inline float2 evalF_t(int u, int v, const float* w9,
                                 const float2* __restrict__ tbl) {
    float fr = 0.f, fi = 0.f;
#pragma unroll
    for (int i = 0; i < 3; ++i) {
#pragma unroll
        for (int j = 0; j < 3; ++j) {
            int idx = u * i + v * j;          // <= 2302
            if (idx >= 2 * HP) idx -= 2 * HP;
            if (idx >= HP)     idx -= HP;
            float2 e = tbl[idx];
            float wv = w9[i * 3 + j];
            fr += wv * e.x;
            fi -= wv * e.y;
        }
    }
    return make_float2(fr, fi);
}

// One block per rfft column v. Builds gmf[.,v] in LDS, then
// P[a,v] = sum_u gmf[u,v] * exp(+2*pi*i*u*(a-K)/768)  for all 17 taps,
// parallelized 16 threads per tap.
__global__ __launch_bounds__(320) void filt_P_kernel(
        const float* __restrict__ w, float2* __restrict__ P) {
    __shared__ float2 tbl[HP];
    __shared__ float2 lg[HP];
    __shared__ float2 red[20][16];
    int v = blockIdx.x;
    int tid = threadIdx.x;

    float w9[9];
#pragma unroll
    for (int i = 0; i < 9; ++i) w9[i] = w[i];

    for (int m = tid; m < HP; m += 320) {
        float s, c;
        sincosf((float)m * TWO_PI_OVER_HP, &s, &c);
        tbl[m] = make_float2(c, s);
    }
    __syncthreads();

    int sv = (v == 0) ? 0 : (NV - v);   // reference's reverse+roll index
    for (int u = tid; u < HP; u += 320) {
        int su = (HP - u) % HP;
        float2 F1 = evalF_t(u,  v,  w9, tbl);
        float2 F2 = evalF_t(su, v,  w9, tbl);
        float2 F3 = evalF_t(u,  sv, w9, tbl);
        float2 F4 = evalF_t(su, sv, w9, tbl);
        float2 pr = cmul(cmul(F1, F2), cmul(F3, F4));
        float d = pr.x * pr.x + pr.y * pr.y;
        lg[u] = make_float2(pr.x / d, -pr.y / d);   // 1/prod
    }
    __syncthreads();

    int a   = tid >> 4;   // 0..19 (taps 0..16 valid)
    int sub = tid & 15;
    if (a < A) {
        int ap  = a - K;
        int apu = (ap < 0) ? ap + HP : ap;
        float Pr = 0.f, Pi = 0.f;
        for (int u = sub; u < HP; u += 16) {
            int idx = (u * apu) % HP;
            float2 e = tbl[idx];
            float2 g = lg[u];
            Pr += g.x * e.x - g.y * e.y;
            Pi += g.x * e.y + g.y * e.x;
        }
        red[a][sub] = make_float2(Pr, Pi);
    }
    __syncthreads();
    if (tid < A) {
        float Pr = 0.f, Pi = 0.f;
#pragma unroll
        for (int s2 = 0; s2 < 16; ++s2) { Pr += red[tid][s2].x; Pi += red[tid][s2].y; }
        P[tid * NV + v] = make_float2(Pr, Pi);
    }
}

// g[a,b] = (1/768^2) * sum_v w_v * Re(P[a,v] * exp(+2*pi*i*v*(b-K)/768))
// Stored FLIPPED: gkf[(16-a)*17 + (16-b)] = g[a,b], so deconv reads ascending.
// One block per tap row ai; P[ai,:] staged to LDS (coalesced) to kill the
// serialized dependent global-load chain of the old 2-block version;
// 16 threads per output tap bi, LDS tree reduce.
__global__ __launch_bounds__(320) void filt_gk_kernel(
        const float2* __restrict__ P, float* __restrict__ gkf) {
    __shared__ float2 tbl[HP];      // 6144 B
    __shared__ float2 Prow[NV];     // 3080 B
    __shared__ float  red[20][16];  // 1280 B
    int ai  = blockIdx.x;           // 0..16
    int tid = threadIdx.x;

    for (int m = tid; m < HP; m += 320) {
        float s, c;
        sincosf((float)m * TWO_PI_OVER_HP, &s, &c);
        tbl[m] = make_float2(c, s);
    }
    for (int m = tid; m < NV; m += 320)
        Prow[m] = P[ai * NV + m];
    __syncthreads();

    int bi  = tid >> 4;   // 0..19 (taps 0..16 valid)
    int sub = tid & 15;
    if (bi < A) {
        int bp  = bi - K;
        int bpu = (bp < 0) ? bp + HP : bp;
        float sum = 0.f;
        for (int vv = sub; vv < NV; vv += 16) {
            float wv = (vv == 0 || vv == NV - 1) ? 1.f : 2.f;
            int idx = (vv * bpu) % HP;
            float2 e = tbl[idx];
            float2 p = Prow[vv];
            sum += wv * (p.x * e.x - p.y * e.y);
        }
        red[bi][sub] = sum;
    }
    __syncthreads();
    if (tid < A) {
        float s = 0.f;
#pragma unroll
        for (int s2 = 0; s2 < 16; ++s2) s += red[tid][s2];
        gkf[(2 * K - ai) * A + (2 * K - tid)] = s * (1.f / ((float)HP * (float)HP));
    }
}

// Zero everything outside the deconv-covered square [OB, OB+9*64) x [OB, OB+9*64).
// One wave per output row; nontemporal float4 stores (write-once data).
__global__ __launch_bounds__(256) void zero_border_kernel(float* __restrict__ out) {
    int gid  = blockIdx.x;            // 64 imgs * 192 row-groups
    int img  = gid / 192;
    int rg   = gid - img * 192;
    int lane = threadIdx.x & 63;
    int w    = threadIdx.x >> 6;      // wave 0..3 -> one row each
    int row  = rg * 4 + w;
    f4v* base = (f4v*)(out + ((size_t)img * HP + row) * HP);
    f4v z = {0.f, 0.f, 0.f, 0.f};
    if (row >= OB && row < OB + NT9 * TH) {
        // side strips: cols [0,120) and [696,768)
        if (lane < ACT0_Q)
            __builtin_nontemporal_store(z, base + lane);
        else if (lane < ACT0_Q + (192 - ACT1_Q))
            __builtin_nontemporal_store(z, base + ACT1_Q + (lane - ACT0_Q));
    } else {
        // full row: 192 float4 = 64 lanes x 3
        __builtin_nontemporal_store(z, base + lane);
        __builtin_nontemporal_store(z, base + lane + 64);
        __builtin_nontemporal_store(z, base + lane + 128);
    }
}

// Direct 17x17 convolution of zero-padded x into the 768x768 output grid,
// tiled over the 9x9 active region only (origin OB=120).
// Block (8,32); tile 64x64 outputs; thread computes 8 cols x 2 adjacent rows
// with a rolling register row-buffer (1 new LDS row per tap).
// launch_bounds(256,6): LDS 27136 B -> exactly 6 blocks/CU (162816<=163840);
// VGPR 52 <= 512/6. Doubles occupancy (11.5 -> ~24 waves/CU) to hide the
// lgkm stalls + 1.97e7 LDS-conflict cycles seen at (256,4).
__global__ __launch_bounds__(256, 6) void deconv_kernel(
        const float* __restrict__ x, const float* __restrict__ gkf,
        float* __restrict__ out) {
    // parity-split tile: even tile-rows in [0], odd in [1] (bank spread)
    __shared__ __align__(16) float tile[2 * HSIZE];   // 26880 B

    const int tx = threadIdx.x;   // 0..7
    const int ty = threadIdx.y;   // 0..31
    const int tid = ty * 8 + tx;
    const int bx = blockIdx.x, by = blockIdx.y, bz = blockIdx.z;

    const int ix0 = bx * TW + (OB - PADO);   // = 64*bx - 16  (% 4 == 0)
    const int iy0 = by * TH + (OB - PADO);
    const int oy0 = OB + by * TH + ty * 2;
    const int ox0 = OB + bx * TW + tx * 8;
    float* orow0 = out + ((size_t)bz * HP + oy0) * HP + ox0;
    float* orow1 = orow0 + HP;

    // stage input tile (float4-granular; ix0 % 4 == 0 so no partial float4)
    const float* xb = x + (size_t)bz * (HIN * WIN);
    for (int l = tid; l < LH * (LWL / 4); l += 256) {   // 80*20 = 1600
        int r = l / 20, c4 = l - r * 20;
        int gy = iy0 + r;
        int gx = ix0 + c4 * 4;
        float4 val = make_float4(0.f, 0.f, 0.f, 0.f);
        if ((unsigned)gy < (unsigned)HIN && (unsigned)gx < (unsigned)WIN)
            val = *(const float4*)&xb[gy * WIN + gx];
        *(float4*)&tile[(r & 1) * HSIZE + (r >> 1) * LWS + c4 * 4] = val;
    }
    __syncthreads();

    // Wave-uniform early-out: output rows >= OE are provably zero (input
    // support ends at padded row 640; taps reach at most +8 => out < 648).
    // ty >= 8 in by==8 tiles -> waves 1..3 retire after staging (saves the
    // full 4624-FMA loop for 48 of 64 rows in the last tile row).
    if (oy0 >= OE) {
        f4v z = {0.f, 0.f, 0.f, 0.f};
        __builtin_nontemporal_store(z, (f4v*)orow0);
        __builtin_nontemporal_store(z, (f4v*)orow0 + 1);
        __builtin_nontemporal_store(z, (f4v*)orow1);
        __builtin_nontemporal_store(z, (f4v*)orow1 + 1);
        return;
    }

    const float* tE = tile;           // tile rows 0,2,4,...
    const float* tO = tile + HSIZE;   // tile rows 1,3,5,...

    float accA[8], accB[8];
#pragma unroll
    for (int c = 0; c < 8; ++c) { accA[c] = 0.f; accB[c] = 0.f; }
    float rbA[24], rbB[24];

    auto loadRow = [&](float* rb, const float* tb, int rowp) {
        const float* p = tb + rowp * LWS + tx * 8;
#pragma unroll
        for (int q = 0; q < 6; ++q)
            *(float4*)&rb[q * 4] = *(const float4*)&p[q * 4];
    };
    // gp is wave-uniform -> scalar loads; v_fmac with SGPR src0.
    // One row, one accumulator: lets the scheduler issue the full 136-FMA
    // block on the resident row before any FMA that waits on in-flight LDS.
    auto fmaRow = [&](const float* gp, const float* r, float* acc) {
#pragma unroll
        for (int bb = 0; bb < A; ++bb) {
            float g = gp[bb];
#pragma unroll
            for (int c = 0; c < 8; ++c)
                acc[c] += g * r[bb + c];
        }
    };

    loadRow(rbA, tE, ty);                      // input tile-row 2ty
#pragma unroll 1
    for (int aa = 0; aa < 16; aa += 2) {
        int h = aa >> 1;
        loadRow(rbB, tO, ty + h);              // row 2ty+aa+1 (in flight)
        fmaRow(gkf + aa * A, rbA, accA);       // tap aa -> out row0 (resident)
        fmaRow(gkf + aa * A, rbB, accB);       // tap aa -> out row1 (waits)
        loadRow(rbA, tE, ty + h + 1);          // row 2ty+aa+2 (in flight)
        fmaRow(gkf + (aa + 1) * A, rbB, accA); // tap aa+1 -> out row0 (resident)
        fmaRow(gkf + (aa + 1) * A, rbA, accB); // tap aa+1 -> out row1 (waits)
    }
    loadRow(rbB, tO, ty + 8);                  // row 2ty+17
    fmaRow(gkf + 16 * A, rbA, accA);           // tap 16
    fmaRow(gkf + 16 * A, rbB, accB);

    f4v vA0 = {accA[0], accA[1], accA[2], accA[3]};
    f4v vA1 = {accA[4], accA[5], accA[6], accA[7]};
    f4v vB0 = {accB[0], accB[1], accB[2], accB[3]};
    f4v vB1 = {accB[4], accB[5], accB[6], accB[7]};
    __builtin_nontemporal_store(vA0, (f4v*)orow0);
    __builtin_nontemporal_store(vA1, (f4v*)orow0 + 1);
    __builtin_nontemporal_store(vB0, (f4v*)orow1);
    __builtin_nontemporal_store(vB1, (f4v*)orow1 + 1);
}

extern "C" void kernel_launch(void* const* d_in, const int* in_sizes, int n_in,
                              void* d_out, int out_size, void* d_ws, size_t ws_size,
                              hipStream_t stream) {
    const float* x = (const float*)d_in[0];   // (64, 512, 512) fp32
    const float* w = (const float*)d_in[1];   // (3, 3) fp32
    float* out = (float*)d_out;               // (64, 768, 768) fp32

    // workspace layout (floats): P = A*NV float2, then gkf = A*A floats
    float2* P   = (float2*)d_ws;
    float*  gkf = (float*)d_ws + (size_t)A * NV * 2;

    filt_P_kernel<<<dim3(NV), dim3(320), 0, stream>>>(w, P);
    filt_gk_kernel<<<dim3(A), dim3(320), 0, stream>>>(P, gkf);
    zero_border_kernel<<<dim3(64 * 192), dim3(256), 0, stream>>>(out);
    deconv_kernel<<<dim3(NT9, NT9, 64), dim3(8, 32), 0, stream>>>(x, gkf, out);
}

// Round 7
// 307.222 us; speedup vs baseline: 1.2394x; 1.0327x over previous
//
#include <hip/hip_runtime.h>

#define HP   768      // padded H (=W)
#define NV   385      // HP/2 + 1
#define HIN  512
#define WIN  512
#define K    8        // truncation radius of spatial inverse kernel
#define A    17       // 2K+1
#define PADO 136      // PAD + K = 128 + 8
#define TW   64       // output tile width
#define TH   64       // output tile height (2 rows per thread)
#define LH   80       // TH + 2K
#define LWL  80       // TW + 2K (logical tile width)
#define LWS  84       // padded LDS row stride (20*ty mod 32 spreads banks)
#define HROWS 40      // rows per parity half-tile
#define HSIZE (HROWS * LWS)   // 3360 floats per half-tile

#define OB   120      // active-region origin: nonzero out rows/cols = [120, 648)
#define OE   648      // active-region end (exclusive)
#define NT9  9        // 9x9 tiles cover [120, 696) >= [120, 648)
#define ACT0_Q 30     // 120/4  (float4 index of active col start)
#define ACT1_Q 174    // 696/4  (float4 index of active col end)

#define TWO_PI_OVER_HP 0.008181230868723419f  // 2*pi/768

typedef float f4v __attribute__((ext_vector_type(4)));

__device__ inline float2 cmul(float2 a, float2 b) {
    return make_float2(a.x*b.x - a.y*b.y, a.x*b.y + a.y*b.x);
}

// F(u,v) = sum_{i<3,j<3} w[i,j] * exp(-2*pi*i*(u*i + v*j)/768), via LDS table
__device__ inline float2 evalF_t(int u, int v, const float* w9,
                                 const float2* __restrict__ tbl) {
    float fr = 0.f, fi = 0.f;
#pragma unroll
    for (int i = 0; i < 3; ++i) {
#pragma unroll
        for (int j = 0; j < 3; ++j) {
            int idx = u * i + v * j;          // <= 2302
            if (idx >= 2 * HP) idx -= 2 * HP;
            if (idx >= HP)     idx -= HP;
            float2 e = tbl[idx];
            float wv = w9[i * 3 + j];
            fr += wv * e.x;
            fi -= wv * e.y;
        }
    }
    return make_float2(fr, fi);
}

// One block per rfft column v. Builds gmf[.,v] in LDS, then
// P[a,v] = sum_u gmf[u,v] * exp(+2*pi*i*u*(a-K)/768)  for all 17 taps,
// parallelized 16 threads per tap.
__global__ __launch_bounds__(320) void filt_P_kernel(
        const float* __restrict__ w, float2* __restrict__ P) {
    __shared__ float2 tbl[HP];
    __shared__ float2 lg[HP];
    __shared__ float2 red[20][16];
    int v = blockIdx.x;
    int tid = threadIdx.x;

    float w9[9];
#pragma unroll
    for (int i = 0; i < 9; ++i) w9[i] = w[i];

    for (int m = tid; m < HP; m += 320) {
        float s, c;
        sincosf((float)m * TWO_PI_OVER_HP, &s, &c);
        tbl[m] = make_float2(c, s);
    }
    __syncthreads();

    int sv = (v == 0) ? 0 : (NV - v);   // reference's reverse+roll index
    for (int u = tid; u < HP; u += 320) {
        int su = (HP - u) % HP;
        float2 F1 = evalF_t(u,  v,  w9, tbl);
        float2 F2 = evalF_t(su, v,  w9, tbl);
        float2 F3 = evalF_t(u,  sv, w9, tbl);
        float2 F4 = evalF_t(su, sv, w9, tbl);
        float2 pr = cmul(cmul(F1, F2), cmul(F3, F4));
        float d = pr.x * pr.x + pr.y * pr.y;
        lg[u] = make_float2(pr.x / d, -pr.y / d);   // 1/prod
    }
    __syncthreads();

    int a   = tid >> 4;   // 0..19 (taps 0..16 valid)
    int sub = tid & 15;
    if (a < A) {
        int ap  = a - K;
        int apu = (ap < 0) ? ap + HP : ap;
        float Pr = 0.f, Pi = 0.f;
        for (int u = sub; u < HP; u += 16) {
            int idx = (u * apu) % HP;
            float2 e = tbl[idx];
            float2 g = lg[u];
            Pr += g.x * e.x - g.y * e.y;
            Pi += g.x * e.y + g.y * e.x;
        }
        red[a][sub] = make_float2(Pr, Pi);
    }
    __syncthreads();
    if (tid < A) {
        float Pr = 0.f, Pi = 0.f;
#pragma unroll
        for (int s2 = 0; s2 < 16; ++s2) { Pr += red[tid][s2].x; Pi += red[tid][s2].y; }
        P[tid * NV + v] = make_float2(Pr, Pi);
    }
}

// g[a,b] = (1/768^2) * sum_v w_v * Re(P[a,v] * exp(+2*pi*i*v*(b-K)/768))
// Stored FLIPPED: gkf[(16-a)*17 + (16-b)] = g[a,b], so deconv reads ascending.
// One block per tap row ai; P[ai,:] staged to LDS (coalesced) to kill the
// serialized dependent global-load chain of the old 2-block version;
// 16 threads per output tap bi, LDS tree reduce.
__global__ __launch_bounds__(320) void filt_gk_kernel(
        const float2* __restrict__ P, float* __restrict__ gkf) {
    __shared__ float2 tbl[HP];      // 6144 B
    __shared__ float2 Prow[NV];     // 3080 B
    __shared__ float  red[20][16];  // 1280 B
    int ai  = blockIdx.x;           // 0..16
    int tid = threadIdx.x;

    for (int m = tid; m < HP; m += 320) {
        float s, c;
        sincosf((float)m * TWO_PI_OVER_HP, &s, &c);
        tbl[m] = make_float2(c, s);
    }
    for (int m = tid; m < NV; m += 320)
        Prow[m] = P[ai * NV + m];
    __syncthreads();

    int bi  = tid >> 4;   // 0..19 (taps 0..16 valid)
    int sub = tid & 15;
    if (bi < A) {
        int bp  = bi - K;
        int bpu = (bp < 0) ? bp + HP : bp;
        float sum = 0.f;
        for (int vv = sub; vv < NV; vv += 16) {
            float wv = (vv == 0 || vv == NV - 1) ? 1.f : 2.f;
            int idx = (vv * bpu) % HP;
            float2 e = tbl[idx];
            float2 p = Prow[vv];
            sum += wv * (p.x * e.x - p.y * e.y);
        }
        red[bi][sub] = sum;
    }
    __syncthreads();
    if (tid < A) {
        float s = 0.f;
#pragma unroll
        for (int s2 = 0; s2 < 16; ++s2) s += red[tid][s2];
        gkf[(2 * K - ai) * A + (2 * K - tid)] = s * (1.f / ((float)HP * (float)HP));
    }
}

// Zero everything outside the deconv-covered square [OB, OB+9*64) x [OB, OB+9*64).
// One wave per output row; nontemporal float4 stores (write-once data).
__global__ __launch_bounds__(256) void zero_border_kernel(float* __restrict__ out) {
    int gid  = blockIdx.x;            // 64 imgs * 192 row-groups
    int img  = gid / 192;
    int rg   = gid - img * 192;
    int lane = threadIdx.x & 63;
    int w    = threadIdx.x >> 6;      // wave 0..3 -> one row each
    int row  = rg * 4 + w;
    f4v* base = (f4v*)(out + ((size_t)img * HP + row) * HP);
    f4v z = {0.f, 0.f, 0.f, 0.f};
    if (row >= OB && row < OB + NT9 * TH) {
        // side strips: cols [0,120) and [696,768)
        if (lane < ACT0_Q)
            __builtin_nontemporal_store(z, base + lane);
        else if (lane < ACT0_Q + (192 - ACT1_Q))
            __builtin_nontemporal_store(z, base + ACT1_Q + (lane - ACT0_Q));
    } else {
        // full row: 192 float4 = 64 lanes x 3
        __builtin_nontemporal_store(z, base + lane);
        __builtin_nontemporal_store(z, base + lane + 64);
        __builtin_nontemporal_store(z, base + lane + 128);
    }
}

// Direct 17x17 convolution of zero-padded x into the 768x768 output grid,
// tiled over the 9x9 active region only (origin OB=120).
// Block (8,32); tile 64x64 outputs; thread computes 8 cols x 2 adjacent rows.
// Row buffers are ext_vector(4) arrays with STATIC indexing only -> guaranteed
// VGPR residency (compiler was re-reading LDS just-in-time at VGPR=52/40,
// stalling on lgkm before every FMA cluster). launch_bounds(256,4): VGPR
// cap 128 (need ~80-100); occupancy 6 regressed (write-amp/L2 thrash).
__global__ __launch_bounds__(256, 4) void deconv_kernel(
        const float* __restrict__ x, const float* __restrict__ gkf,
        float* __restrict__ out) {
    // parity-split tile: even tile-rows in [0], odd in [1] (bank spread)
    __shared__ __align__(16) float tile[2 * HSIZE];   // 26880 B

    const int tx = threadIdx.x;   // 0..7
    const int ty = threadIdx.y;   // 0..31
    const int tid = ty * 8 + tx;
    const int bx = blockIdx.x, by = blockIdx.y, bz = blockIdx.z;

    const int ix0 = bx * TW + (OB - PADO);   // = 64*bx - 16  (% 4 == 0)
    const int iy0 = by * TH + (OB - PADO);
    const int oy0 = OB + by * TH + ty * 2;
    const int ox0 = OB + bx * TW + tx * 8;
    float* orow0 = out + ((size_t)bz * HP + oy0) * HP + ox0;
    float* orow1 = orow0 + HP;

    // stage input tile (float4-granular; ix0 % 4 == 0 so no partial float4)
    const float* xb = x + (size_t)bz * (HIN * WIN);
    for (int l = tid; l < LH * (LWL / 4); l += 256) {   // 80*20 = 1600
        int r = l / 20, c4 = l - r * 20;
        int gy = iy0 + r;
        int gx = ix0 + c4 * 4;
        f4v val = {0.f, 0.f, 0.f, 0.f};
        if ((unsigned)gy < (unsigned)HIN && (unsigned)gx < (unsigned)WIN)
            val = *(const f4v*)&xb[gy * WIN + gx];
        *(f4v*)&tile[(r & 1) * HSIZE + (r >> 1) * LWS + c4 * 4] = val;
    }
    __syncthreads();

    // Wave-uniform early-out: output rows >= OE are provably zero (input
    // support ends at padded row 640; taps reach at most +8 => out < 648).
    if (oy0 >= OE) {
        f4v z = {0.f, 0.f, 0.f, 0.f};
        __builtin_nontemporal_store(z, (f4v*)orow0);
        __builtin_nontemporal_store(z, (f4v*)orow0 + 1);
        __builtin_nontemporal_store(z, (f4v*)orow1);
        __builtin_nontemporal_store(z, (f4v*)orow1 + 1);
        return;
    }

    const float* tE = tile;           // tile rows 0,2,4,...
    const float* tO = tile + HSIZE;   // tile rows 1,3,5,...

    float accA[8], accB[8];
#pragma unroll
    for (int c = 0; c < 8; ++c) { accA[c] = 0.f; accB[c] = 0.f; }

    // 24-float row windows held as 6 x f4v (one ds_read_b128 each).
    f4v rbA[6], rbB[6];

    auto loadRow = [&](f4v* rb, const float* tb, int rowp) {
        const float* p = tb + rowp * LWS + tx * 8;
#pragma unroll
        for (int q = 0; q < 6; ++q)
            rb[q] = *(const f4v*)&p[q * 4];
    };
    // gp wave-uniform -> s_load; v_fmac_f32 acc, sG, vCur.
    // All rb indices compile-time constant: (bb+c)>>2 / (bb+c)&3.
    auto fmaRow = [&](const float* gp, const f4v* r, float* acc) {
#pragma unroll
        for (int bb = 0; bb < A; ++bb) {
            float g = gp[bb];
#pragma unroll
            for (int c = 0; c < 8; ++c) {
                int i = bb + c;
                acc[c] += g * r[i >> 2][i & 3];
            }
        }
    };

    loadRow(rbA, tE, ty);                      // input tile-row 2ty
#pragma unroll 1
    for (int aa = 0; aa < 16; aa += 2) {
        int h = aa >> 1;
        loadRow(rbB, tO, ty + h);              // row 2ty+aa+1 (in flight)
        fmaRow(gkf + aa * A, rbA, accA);       // tap aa -> out row0 (resident)
        fmaRow(gkf + aa * A, rbB, accB);       // tap aa -> out row1 (waits)
        loadRow(rbA, tE, ty + h + 1);          // row 2ty+aa+2 (in flight)
        fmaRow(gkf + (aa + 1) * A, rbB, accA); // tap aa+1 -> out row0 (resident)
        fmaRow(gkf + (aa + 1) * A, rbA, accB); // tap aa+1 -> out row1 (waits)
    }
    loadRow(rbB, tO, ty + 8);                  // row 2ty+17
    fmaRow(gkf + 16 * A, rbA, accA);           // tap 16
    fmaRow(gkf + 16 * A, rbB, accB);

    f4v vA0 = {accA[0], accA[1], accA[2], accA[3]};
    f4v vA1 = {accA[4], accA[5], accA[6], accA[7]};
    f4v vB0 = {accB[0], accB[1], accB[2], accB[3]};
    f4v vB1 = {accB[4], accB[5], accB[6], accB[7]};
    __builtin_nontemporal_store(vA0, (f4v*)orow0);
    __builtin_nontemporal_store(vA1, (f4v*)orow0 + 1);
    __builtin_nontemporal_store(vB0, (f4v*)orow1);
    __builtin_nontemporal_store(vB1, (f4v*)orow1 + 1);
}

extern "C" void kernel_launch(void* const* d_in, const int* in_sizes, int n_in,
                              void* d_out, int out_size, void* d_ws, size_t ws_size,
                              hipStream_t stream) {
    const float* x = (const float*)d_in[0];   // (64, 512, 512) fp32
    const float* w = (const float*)d_in[1];   // (3, 3) fp32
    float* out = (float*)d_out;               // (64, 768, 768) fp32

    // workspace layout (floats): P = A*NV float2, then gkf = A*A floats
    float2* P   = (float2*)d_ws;
    float*  gkf = (float*)d_ws + (size_t)A * NV * 2;

    filt_P_kernel<<<dim3(NV), dim3(320), 0, stream>>>(w, P);
    filt_gk_kernel<<<dim3(A), dim3(320), 0, stream>>>(P, gkf);
    zero_border_kernel<<<dim3(64 * 192), dim3(256), 0, stream>>>(out);
    deconv_kernel<<<dim3(NT9, NT9, 64), dim3(8, 32), 0, stream>>>(x, gkf, out);
}